// Round 1
// baseline (471.566 us; speedup 1.0000x reference)
//
#include <hip/hip_runtime.h>
#include <cstdint>
#include <cstddef>

// ---------------------------------------------------------------------------
// MultiheadSelectiveAttention (B=2, S=2048, D=1024, H=16, dh=64), fp32 in/out.
// Pipeline:
//   cast X,Wq,Wk (hi/lo bf16 split) + Wv,Wo (bf16)
//   XQ = X@Wq^T (3-pass split MFMA, fp32) -> LN -> Qh bf16 (+ head0 lo)
//   XK likewise -> Kh (+ head0 lo)
//   XV = X@Wv^T (1-pass) -> V^T bf16 (b,h,d,n)
//   S0[b,j,m] = relu(mask(Q0 K0^T / 8))   (3-pass split MFMA, fp32, 33.5MB)
//   F = exclusive-cumsum_n(S0) (3-kernel segmented scan, in place)
//   flash attention per (b,h,128-row tile): S^T=K Q^T MFMA, online softmax
//     with F subtraction, P->LDS->PV MFMA with V^T, -> Obuf bf16
//   out = Obuf @ Wo^T (1-pass MFMA, fp32) -> d_out
// d_out is reused as the fp32 GEMM scratch before the final GEMM.
// ---------------------------------------------------------------------------

typedef unsigned short u16;
typedef __attribute__((ext_vector_type(8))) __bf16 bf16x8;
typedef __attribute__((ext_vector_type(4))) float f32x4;

#define D_MODEL 1024
#define N_HEADS 16
#define BATCH   2
#define SEQ     2048
#define D_HEAD  64
#define ROWS    (BATCH*SEQ)   /* 4096 */
#define NSEG    16
#define SEGLEN  128

static __device__ __forceinline__ u16 f2bf(float f){
  union { float f; uint32_t u; } v; v.f = f;
  uint32_t r = v.u + 0x7fffu + ((v.u >> 16) & 1u);
  return (u16)(r >> 16);
}
static __device__ __forceinline__ float bf2f(u16 h){
  union { uint32_t u; float f; } v; v.u = ((uint32_t)h) << 16;
  return v.f;
}

// ------------------------------ cast kernels -------------------------------
__global__ void k_cast_split(const float* __restrict__ x, u16* __restrict__ hi,
                             u16* __restrict__ lo, int n4){
  int i = blockIdx.x*256 + threadIdx.x;
  if (i >= n4) return;
  float4 v = reinterpret_cast<const float4*>(x)[i];
  float vs[4] = {v.x, v.y, v.z, v.w};
  union { u16 s[4]; uint2 u; } uh, ul;
#pragma unroll
  for (int r=0;r<4;++r){
    uh.s[r] = f2bf(vs[r]);
    ul.s[r] = f2bf(vs[r] - bf2f(uh.s[r]));
  }
  reinterpret_cast<uint2*>(hi)[i] = uh.u;
  reinterpret_cast<uint2*>(lo)[i] = ul.u;
}

__global__ void k_cast(const float* __restrict__ x, u16* __restrict__ hi, int n4){
  int i = blockIdx.x*256 + threadIdx.x;
  if (i >= n4) return;
  float4 v = reinterpret_cast<const float4*>(x)[i];
  float vs[4] = {v.x, v.y, v.z, v.w};
  union { u16 s[4]; uint2 u; } uh;
#pragma unroll
  for (int r=0;r<4;++r) uh.s[r] = f2bf(vs[r]);
  reinterpret_cast<uint2*>(hi)[i] = uh.u;
}

// ------------------------- generic NT GEMM (bf16 MFMA) ---------------------
// C[M,N] += sum_p A_p[M,K] * B_p[N,K]^T ; K row stride == K. 128x128 tile.
__global__ __launch_bounds__(256) void k_gemm_nt(
    const u16* A0, const u16* B0, const u16* A1, const u16* B1,
    const u16* A2, const u16* B2, int npass,
    float* __restrict__ C, int M, int N, int K)
{
  __shared__ __align__(16) u16 As[128*32];
  __shared__ __align__(16) u16 Bs[128*32];
  const int tid = threadIdx.x, wv = tid>>6, ln = tid&63;
  const int lane15 = ln&15, quad = ln>>4;
  const int wm = wv&1, wn = wv>>1;
  const size_t rowBase = (size_t)blockIdx.y*128, colBase = (size_t)blockIdx.x*128;
  f32x4 acc[4][4];
  f32x4 z = {0.f,0.f,0.f,0.f};
#pragma unroll
  for (int i=0;i<4;++i)
#pragma unroll
    for (int j=0;j<4;++j) acc[i][j] = z;
  const u16* Aps[3] = {A0, A1, A2};
  const u16* Bps[3] = {B0, B1, B2};
  const int ktiles = K >> 5;
  const int sRow = ln>>2, sCol = (ln&3)*8;
  for (int p = 0; p < npass; ++p) {
    const u16* Ap = Aps[p];
    const u16* Bp = Bps[p];
    for (int kt = 0; kt < ktiles; ++kt) {
      __syncthreads();
#pragma unroll
      for (int c = 0; c < 2; ++c) {
        int chunk = wv*2 + c;                 // 0..7 -> 16-row slab of LDS tile
        int r = chunk*16 + sRow;
        const u16* ga = Ap + (rowBase + r)*K + kt*32 + sCol;
        const u16* gb = Bp + (colBase + r)*K + kt*32 + sCol;
        __builtin_amdgcn_global_load_lds(
            (const __attribute__((address_space(1))) void*)ga,
            (__attribute__((address_space(3))) void*)(As + chunk*512), 16, 0, 0);
        __builtin_amdgcn_global_load_lds(
            (const __attribute__((address_space(1))) void*)gb,
            (__attribute__((address_space(3))) void*)(Bs + chunk*512), 16, 0, 0);
      }
      __syncthreads();
      bf16x8 af[4], bfb[4];
#pragma unroll
      for (int t=0;t<4;++t){
        af[t]  = *reinterpret_cast<const bf16x8*>(As + (wm*64 + t*16 + lane15)*32 + quad*8);
        bfb[t] = *reinterpret_cast<const bf16x8*>(Bs + (wn*64 + t*16 + lane15)*32 + quad*8);
      }
#pragma unroll
      for (int i=0;i<4;++i)
#pragma unroll
        for (int j=0;j<4;++j)
          acc[i][j] = __builtin_amdgcn_mfma_f32_16x16x32_bf16(af[i], bfb[j], acc[i][j], 0,0,0);
    }
  }
#pragma unroll
  for (int i=0;i<4;++i){
    size_t row = rowBase + wm*64 + i*16 + quad*4;
#pragma unroll
    for (int j=0;j<4;++j){
      size_t col = colBase + wn*64 + j*16 + lane15;
#pragma unroll
      for (int r=0;r<4;++r)
        C[(row+r)*N + col] = acc[i][j][r];
    }
  }
}

// ----------------- head-0 scores: S0 = relu(mask(Q0 K0^T / 8)) -------------
__global__ __launch_bounds__(256) void k_s0(
    const u16* Qh, const u16* Q0l, const u16* Kh, const u16* K0l,
    float* __restrict__ S0)
{
  const int b = blockIdx.z;
  const int bm = blockIdx.y;  // j (query-row) tile
  const int bn = blockIdx.x;  // m (key-col) tile
  float* Sb = S0 + (size_t)b*SEQ*SEQ;
  const int tid = threadIdx.x;
  if (bn > bm){               // fully above diagonal -> zeros
    float4 zz = {0.f,0.f,0.f,0.f};
    for (int t = tid; t < 128*32; t += 256){
      int r = t >> 5, c = t & 31;
      reinterpret_cast<float4*>(Sb + (size_t)(bm*128 + r)*SEQ + bn*128)[c] = zz;
    }
    return;
  }
  __shared__ __align__(16) u16 As[128*32];
  __shared__ __align__(16) u16 Bs[128*32];
  const int wv = tid>>6, ln = tid&63;
  const int lane15 = ln&15, quad = ln>>4;
  const int wm = wv&1, wn = wv>>1;
  f32x4 acc[4][4];
  f32x4 z = {0.f,0.f,0.f,0.f};
#pragma unroll
  for (int i=0;i<4;++i)
#pragma unroll
    for (int j=0;j<4;++j) acc[i][j] = z;
  const u16* Qb  = Qh  + (size_t)b*N_HEADS*SEQ*D_HEAD;   // head 0 block
  const u16* Kb  = Kh  + (size_t)b*N_HEADS*SEQ*D_HEAD;
  const u16* Qlb = Q0l + (size_t)b*SEQ*D_HEAD;
  const u16* Klb = K0l + (size_t)b*SEQ*D_HEAD;
  const u16* Aps[3] = {Qb, Qb, Qlb};
  const u16* Bps[3] = {Kb, Klb, Kb};
  const int sRow = ln>>2, sCol = (ln&3)*8;
  const size_t rowBase = (size_t)bm*128, colBase = (size_t)bn*128;
  for (int p = 0; p < 3; ++p) {
    const u16* Ap = Aps[p];
    const u16* Bp = Bps[p];
    for (int kt = 0; kt < 2; ++kt) {
      __syncthreads();
#pragma unroll
      for (int c = 0; c < 2; ++c) {
        int chunk = wv*2 + c;
        int r = chunk*16 + sRow;
        const u16* ga = Ap + (rowBase + r)*D_HEAD + kt*32 + sCol;
        const u16* gb = Bp + (colBase + r)*D_HEAD + kt*32 + sCol;
        __builtin_amdgcn_global_load_lds(
            (const __attribute__((address_space(1))) void*)ga,
            (__attribute__((address_space(3))) void*)(As + chunk*512), 16, 0, 0);
        __builtin_amdgcn_global_load_lds(
            (const __attribute__((address_space(1))) void*)gb,
            (__attribute__((address_space(3))) void*)(Bs + chunk*512), 16, 0, 0);
      }
      __syncthreads();
      bf16x8 af[4], bfb[4];
#pragma unroll
      for (int t=0;t<4;++t){
        af[t]  = *reinterpret_cast<const bf16x8*>(As + (wm*64 + t*16 + lane15)*32 + quad*8);
        bfb[t] = *reinterpret_cast<const bf16x8*>(Bs + (wn*64 + t*16 + lane15)*32 + quad*8);
      }
#pragma unroll
      for (int i=0;i<4;++i)
#pragma unroll
        for (int j=0;j<4;++j)
          acc[i][j] = __builtin_amdgcn_mfma_f32_16x16x32_bf16(af[i], bfb[j], acc[i][j], 0,0,0);
    }
  }
#pragma unroll
  for (int i=0;i<4;++i){
#pragma unroll
    for (int j=0;j<4;++j){
#pragma unroll
      for (int r=0;r<4;++r){
        int jg = (int)rowBase + wm*64 + i*16 + quad*4 + r;
        int mg = (int)colBase + wn*64 + j*16 + lane15;
        float l = acc[i][j][r]*0.125f;
        float s = (mg >= 1 && mg < jg) ? fmaxf(l, 0.f) : 0.f;
        Sb[(size_t)jg*SEQ + mg] = s;
      }
    }
  }
}

// -------------------- LN + pack to bf16 head layout ------------------------
__global__ __launch_bounds__(256) void k_ln_pack(
    const float* __restrict__ Xp, const float* __restrict__ g,
    const float* __restrict__ bb, u16* __restrict__ Oh, u16* __restrict__ Olo)
{
  const int row = blockIdx.x;
  const int tid = threadIdx.x;
  const float* xr = Xp + (size_t)row*D_MODEL;
  float4 v = reinterpret_cast<const float4*>(xr)[tid];
  float s  = v.x+v.y+v.z+v.w;
  float s2 = v.x*v.x+v.y*v.y+v.z*v.z+v.w*v.w;
#pragma unroll
  for (int o=32;o;o>>=1){ s += __shfl_xor(s,o); s2 += __shfl_xor(s2,o); }
  __shared__ float ps[4], ps2[4];
  if ((tid&63)==0){ ps[tid>>6]=s; ps2[tid>>6]=s2; }
  __syncthreads();
  s  = ps[0]+ps[1]+ps[2]+ps[3];
  s2 = ps2[0]+ps2[1]+ps2[2]+ps2[3];
  const float mu  = s*(1.f/D_MODEL);
  const float var = s2*(1.f/D_MODEL) - mu*mu;
  const float rs  = rsqrtf(var + 1e-5f);
  const int b = row >> 11, n = row & (SEQ-1);
  const int j0 = tid*4, h = j0 >> 6, d0 = j0 & 63;
  float4 gv = reinterpret_cast<const float4*>(g)[tid];
  float4 bv = reinterpret_cast<const float4*>(bb)[tid];
  float xs[4] = {v.x,v.y,v.z,v.w};
  float gs[4] = {gv.x,gv.y,gv.z,gv.w};
  float bs[4] = {bv.x,bv.y,bv.z,bv.w};
  union { u16 s[4]; uint2 u; } uh, ul;
#pragma unroll
  for (int r=0;r<4;++r){
    float y = (xs[r]-mu)*rs*gs[r] + bs[r];
    uh.s[r] = f2bf(y);
    ul.s[r] = f2bf(y - bf2f(uh.s[r]));
  }
  u16* dst = Oh + (((size_t)(b*N_HEADS + h))*SEQ + n)*D_HEAD + d0;
  *reinterpret_cast<uint2*>(dst) = uh.u;
  if (h == 0){
    u16* dl = Olo + ((size_t)b*SEQ + n)*D_HEAD + d0;
    *reinterpret_cast<uint2*>(dl) = ul.u;
  }
}

// ------------------------- V -> V^T bf16 (b,h,d,n) -------------------------
__global__ void k_vt_pack(const float* __restrict__ XV, u16* __restrict__ Vt){
  int t = blockIdx.x*256 + threadIdx.x;   // [ (bh*256 + c)*64 + d ]
  int d  = t & 63;
  int c  = (t >> 6) & 255;
  int bh = t >> 14;                        // 0..31
  int b = bh >> 4, h = bh & 15;
  int n0 = c*8;
  union { u16 s[8]; uint4 u; } o;
#pragma unroll
  for (int i=0;i<8;++i)
    o.s[i] = f2bf(XV[((size_t)(b*SEQ + n0 + i))*D_MODEL + h*64 + d]);
  *reinterpret_cast<uint4*>(Vt + ((size_t)bh*D_HEAD + d)*SEQ + n0) = o.u;
}

// -------------------- segmented exclusive cumsum over n --------------------
__global__ void k_seg_sum(const float* __restrict__ S0, float* __restrict__ seg){
  int m = blockIdx.x*256 + threadIdx.x;
  int s = blockIdx.y, b = blockIdx.z;
  const float* Sb = S0 + (size_t)b*SEQ*SEQ;
  float acc = 0.f;
  for (int i=0;i<SEGLEN;++i) acc += Sb[(size_t)(s*SEGLEN + i)*SEQ + m];
  seg[((size_t)b*NSEG + s)*SEQ + m] = acc;
}
__global__ void k_seg_scan(float* __restrict__ seg){
  int m = blockIdx.x*256 + threadIdx.x;
  int b = blockIdx.y;
  float run = 0.f;
#pragma unroll
  for (int s=0;s<NSEG;++s){
    size_t idx = ((size_t)b*NSEG + s)*SEQ + m;
    float t = seg[idx]; seg[idx] = run; run += t;
  }
}
__global__ void k_seg_apply(float* __restrict__ SF, const float* __restrict__ seg){
  int m = blockIdx.x*256 + threadIdx.x;
  int s = blockIdx.y, b = blockIdx.z;
  float run = seg[((size_t)b*NSEG + s)*SEQ + m];
  float* Sb = SF + (size_t)b*SEQ*SEQ;
  for (int i=0;i<SEGLEN;++i){
    size_t idx = (size_t)(s*SEGLEN + i)*SEQ + m;
    float t = Sb[idx]; Sb[idx] = run; run += t;
  }
}

// ----------------------- flash attention with F-mask -----------------------
__global__ __launch_bounds__(256) void k_attn(
    const u16* __restrict__ Qh, const u16* __restrict__ Kh,
    const u16* __restrict__ Vt, const float* __restrict__ F,
    u16* __restrict__ Ob)
{
  __shared__ __align__(16) u16 Ks[128*72];
  __shared__ __align__(16) u16 Vs[64*136];
  __shared__ __align__(16) u16 Ps[128*136];
  __shared__ __align__(16) float alphas[128];
  __shared__ __align__(16) float lsums[128];
  const int h = blockIdx.x, b = blockIdx.z;
  const int nt = b ? (int)(gridDim.y - 1 - blockIdx.y) : (int)blockIdx.y; // balance causal work
  const int tid = threadIdx.x, wv = tid>>6, ln = tid&63;
  const int lane15 = ln&15, quad = ln>>4;
  const u16* Qbh = Qh + ((size_t)(b*N_HEADS + h))*SEQ*D_HEAD;
  const u16* Kbh = Kh + ((size_t)(b*N_HEADS + h))*SEQ*D_HEAD;
  const u16* Vbh = Vt + ((size_t)(b*N_HEADS + h))*D_HEAD*SEQ;
  const float* Fb = F + (size_t)b*SEQ*SEQ;

  bf16x8 qf[2][2];
#pragma unroll
  for (int ns=0; ns<2; ++ns)
#pragma unroll
    for (int kt=0; kt<2; ++kt){
      int n = nt*128 + wv*32 + ns*16 + lane15;
      qf[ns][kt] = *reinterpret_cast<const bf16x8*>(Qbh + (size_t)n*D_HEAD + kt*32 + quad*8);
    }
  float m_run[2] = {-1e30f, -1e30f};
  float l_run[2] = {0.f, 0.f};
  f32x4 acc_o[2][4];
  f32x4 z = {0.f,0.f,0.f,0.f};
#pragma unroll
  for (int mo=0;mo<2;++mo)
#pragma unroll
    for (int no=0;no<4;++no) acc_o[mo][no] = z;

  for (int mt = 0; mt <= nt; ++mt) {
    __syncthreads();
    // stage K tile (128 x 64, row stride 72) and V^T tile (64 x 128, stride 136)
#pragma unroll
    for (int rnd=0;rnd<4;++rnd){
      int ch = rnd*256 + tid;
      int r = ch >> 3, c = (ch & 7)*8;
      *reinterpret_cast<uint4*>(Ks + r*72 + c) =
        *reinterpret_cast<const uint4*>(Kbh + (size_t)(mt*128 + r)*D_HEAD + c);
    }
#pragma unroll
    for (int rnd=0;rnd<4;++rnd){
      int ch = rnd*256 + tid;
      int d = ch >> 4, c = (ch & 15)*8;
      *reinterpret_cast<uint4*>(Vs + d*136 + c) =
        *reinterpret_cast<const uint4*>(Vbh + (size_t)d*SEQ + mt*128 + c);
    }
    __syncthreads();

    // S^T tile: rows m (8 sub), cols n (2 sub per wave)
    f32x4 accs[8][2];
#pragma unroll
    for (int ms=0;ms<8;++ms){ accs[ms][0] = z; accs[ms][1] = z; }
#pragma unroll
    for (int kt=0; kt<2; ++kt){
#pragma unroll
      for (int ms=0; ms<8; ++ms){
        bf16x8 a = *reinterpret_cast<const bf16x8*>(Ks + (ms*16 + lane15)*72 + kt*32 + quad*8);
#pragma unroll
        for (int ns=0; ns<2; ++ns)
          accs[ms][ns] = __builtin_amdgcn_mfma_f32_16x16x32_bf16(a, qf[ns][kt], accs[ms][ns], 0,0,0);
      }
    }
    const bool diag = (mt == nt);
#pragma unroll
    for (int ns=0; ns<2; ++ns){
      int n_loc = wv*32 + ns*16 + lane15;
      int n_g = nt*128 + n_loc;
      const float* Fr = Fb + (size_t)n_g*SEQ + mt*128;
      float mx = -1e30f;
#pragma unroll
      for (int ms=0; ms<8; ++ms){
        f32x4 fv = *reinterpret_cast<const f32x4*>(Fr + ms*16 + quad*4);
        f32x4 t = accs[ms][ns];
#pragma unroll
        for (int r=0;r<4;++r){
          int m_g = mt*128 + ms*16 + quad*4 + r;
          float l = t[r]*0.125f - fv[r];
          if (diag && m_g > n_g) l = -1e30f;
          t[r] = l;
          mx = fmaxf(mx, l);
        }
        accs[ms][ns] = t;
      }
      mx = fmaxf(mx, __shfl_xor(mx, 16));
      mx = fmaxf(mx, __shfl_xor(mx, 32));
      float mnew = fmaxf(m_run[ns], mx);
      float alpha = __expf(m_run[ns] - mnew);
      float psum = 0.f;
#pragma unroll
      for (int ms=0; ms<8; ++ms){
        f32x4 t = accs[ms][ns];
        union { u16 s[4]; uint2 u; } pk;
#pragma unroll
        for (int r=0;r<4;++r){
          float p = __expf(t[r] - mnew);
          psum += p;
          pk.s[r] = f2bf(p);
        }
        *reinterpret_cast<uint2*>(Ps + n_loc*136 + ms*16 + quad*4) = pk.u;
      }
      psum += __shfl_xor(psum, 16);
      psum += __shfl_xor(psum, 32);
      l_run[ns] = l_run[ns]*alpha + psum;
      m_run[ns] = mnew;
      if (ln < 16) alphas[wv*32 + ns*16 + ln] = alpha;
    }
    // PV: O[n][d] += P[n][m] * V^T[d][m]
#pragma unroll
    for (int mo=0; mo<2; ++mo){
      f32x4 al = *reinterpret_cast<const f32x4*>(&alphas[wv*32 + mo*16 + quad*4]);
#pragma unroll
      for (int no=0; no<4; ++no) acc_o[mo][no] *= al;
    }
#pragma unroll
    for (int kt=0; kt<4; ++kt){
      bf16x8 pa[2];
#pragma unroll
      for (int mo=0;mo<2;++mo)
        pa[mo] = *reinterpret_cast<const bf16x8*>(Ps + (wv*32 + mo*16 + lane15)*136 + kt*32 + quad*8);
#pragma unroll
      for (int no=0; no<4; ++no){
        bf16x8 vb = *reinterpret_cast<const bf16x8*>(Vs + (no*16 + lane15)*136 + kt*32 + quad*8);
#pragma unroll
        for (int mo=0;mo<2;++mo)
          acc_o[mo][no] = __builtin_amdgcn_mfma_f32_16x16x32_bf16(pa[mo], vb, acc_o[mo][no], 0,0,0);
      }
    }
  }
#pragma unroll
  for (int ns=0; ns<2; ++ns)
    if (ln < 16) lsums[wv*32 + ns*16 + ln] = l_run[ns];
#pragma unroll
  for (int mo=0; mo<2; ++mo){
    f32x4 ls = *reinterpret_cast<const f32x4*>(&lsums[wv*32 + mo*16 + quad*4]);
#pragma unroll
    for (int no=0; no<4; ++no){
#pragma unroll
      for (int r=0;r<4;++r){
        float o = acc_o[mo][no][r] / ls[r];
        int n_g = nt*128 + wv*32 + mo*16 + quad*4 + r;
        Ob[((size_t)(b*SEQ + n_g))*D_MODEL + h*64 + no*16 + lane15] = f2bf(o);
      }
    }
  }
}

// ------------------------------- launcher ----------------------------------
extern "C" void kernel_launch(void* const* d_in, const int* in_sizes, int n_in,
                              void* d_out, int out_size, void* d_ws, size_t ws_size,
                              hipStream_t stream)
{
  (void)in_sizes; (void)n_in; (void)out_size; (void)ws_size;
  const float* X  = (const float*)d_in[0];
  const float* Wq = (const float*)d_in[1];
  const float* Wk = (const float*)d_in[2];
  const float* Wv = (const float*)d_in[3];
  const float* Wo = (const float*)d_in[4];
  const float* gq = (const float*)d_in[5];
  const float* bq = (const float*)d_in[6];
  const float* gk = (const float*)d_in[7];
  const float* bk = (const float*)d_in[8];
  float* out = (float*)d_out;

  char* ws = (char*)d_ws;
  size_t off = 0;
  auto alloc = [&](size_t bytes)->char*{
    char* p = ws + off; off += (bytes + 255) & ~(size_t)255; return p;
  };
  u16* Xhi = (u16*)alloc((size_t)ROWS*D_MODEL*2);
  u16* Xlo = (u16*)alloc((size_t)ROWS*D_MODEL*2);
  u16* Wqh = (u16*)alloc((size_t)D_MODEL*D_MODEL*2);
  u16* Wql = (u16*)alloc((size_t)D_MODEL*D_MODEL*2);
  u16* Wkh = (u16*)alloc((size_t)D_MODEL*D_MODEL*2);
  u16* Wkl = (u16*)alloc((size_t)D_MODEL*D_MODEL*2);
  u16* Wvb = (u16*)alloc((size_t)D_MODEL*D_MODEL*2);
  u16* Wob = (u16*)alloc((size_t)D_MODEL*D_MODEL*2);
  u16* Qhp = (u16*)alloc((size_t)BATCH*N_HEADS*SEQ*D_HEAD*2);
  u16* Khp = (u16*)alloc((size_t)BATCH*N_HEADS*SEQ*D_HEAD*2);
  u16* Q0l = (u16*)alloc((size_t)BATCH*SEQ*D_HEAD*2);
  u16* K0l = (u16*)alloc((size_t)BATCH*SEQ*D_HEAD*2);
  u16* Vtp = (u16*)alloc((size_t)BATCH*N_HEADS*D_HEAD*SEQ*2);
  u16* Obf = (u16*)alloc((size_t)ROWS*D_MODEL*2);
  float* Seg = (float*)alloc((size_t)BATCH*NSEG*SEQ*4);
  float* SF  = (float*)alloc((size_t)BATCH*SEQ*SEQ*4);
  float* C32 = out;   // reuse d_out (4096x1024 f32) as GEMM scratch

  const int nX4 = ROWS*D_MODEL/4, nW4 = D_MODEL*D_MODEL/4;
  k_cast_split<<<(nX4+255)/256, 256, 0, stream>>>(X, Xhi, Xlo, nX4);
  k_cast_split<<<(nW4+255)/256, 256, 0, stream>>>(Wq, Wqh, Wql, nW4);
  k_cast_split<<<(nW4+255)/256, 256, 0, stream>>>(Wk, Wkh, Wkl, nW4);
  k_cast<<<(nW4+255)/256, 256, 0, stream>>>(Wv, Wvb, nW4);
  k_cast<<<(nW4+255)/256, 256, 0, stream>>>(Wo, Wob, nW4);

  dim3 gg(D_MODEL/128, ROWS/128);
  // Q projection (split 3-pass), LN, pack
  k_gemm_nt<<<gg, 256, 0, stream>>>(Xhi, Wqh, Xhi, Wql, Xlo, Wqh, 3, C32,
                                    ROWS, D_MODEL, D_MODEL);
  k_ln_pack<<<ROWS, 256, 0, stream>>>(C32, gq, bq, Qhp, Q0l);
  // K projection
  k_gemm_nt<<<gg, 256, 0, stream>>>(Xhi, Wkh, Xhi, Wkl, Xlo, Wkh, 3, C32,
                                    ROWS, D_MODEL, D_MODEL);
  k_ln_pack<<<ROWS, 256, 0, stream>>>(C32, gk, bk, Khp, K0l);
  // V projection + transpose-pack
  k_gemm_nt<<<gg, 256, 0, stream>>>(Xhi, Wvb, Xhi, Wvb, Xhi, Wvb, 1, C32,
                                    ROWS, D_MODEL, D_MODEL);
  k_vt_pack<<<BATCH*N_HEADS*64, 256, 0, stream>>>(C32, Vtp);
  // head-0 scores and F cumsum (in place on SF)
  k_s0<<<dim3(SEQ/128, SEQ/128, BATCH), 256, 0, stream>>>(Qhp, Q0l, Khp, K0l, SF);
  k_seg_sum<<<dim3(SEQ/256, NSEG, BATCH), 256, 0, stream>>>(SF, Seg);
  k_seg_scan<<<dim3(SEQ/256, BATCH), 256, 0, stream>>>(Seg);
  k_seg_apply<<<dim3(SEQ/256, NSEG, BATCH), 256, 0, stream>>>(SF, Seg);
  // attention
  k_attn<<<dim3(N_HEADS, SEQ/128, BATCH), 256, 0, stream>>>(Qhp, Khp, Vtp, SF, Obf);
  // output projection
  k_gemm_nt<<<gg, 256, 0, stream>>>(Obf, Wob, Obf, Wob, Obf, Wob, 1, out,
                                    ROWS, D_MODEL, D_MODEL);
}

// Round 2
// 364.146 us; speedup vs baseline: 1.2950x; 1.2950x over previous
//
#include <hip/hip_runtime.h>
#include <cstdint>
#include <cstddef>

// ---------------------------------------------------------------------------
// MultiheadSelectiveAttention (B=2, S=2048, D=1024, H=16, dh=64), fp32 in/out.
//   cast X (hi/lo), Wq+Wk merged (hi/lo), Wv, Wo (bf16)
//   [XQ|XK] = X@[Wq;Wk]^T (3-pass split MFMA, N=2048) -> LN -> Q/K bf16 packs
//   XV = X@Wv^T (1-pass, 128x64 tiles) -> V^T bf16
//   S0 = relu(mask(Q0 K0^T/8)) 3-pass + fused per-segment column sums
//   F  = exclusive cumsum (seg scan + apply)
//   attention: 64-row Q tiles, 64-col K chunks, swizzled global_load_lds
//     staging, in-register P (quad-shuffle relayout), online softmax w/ F
//   out = Obf @ Wo^T (1-pass, 128x64 tiles)
// ---------------------------------------------------------------------------

typedef unsigned short u16;
typedef __attribute__((ext_vector_type(8))) __bf16 bf16x8;
typedef __attribute__((ext_vector_type(4))) float f32x4;

#define D_MODEL 1024
#define N_HEADS 16
#define BATCH   2
#define SEQ     2048
#define D_HEAD  64
#define ROWS    (BATCH*SEQ)   /* 4096 */
#define NSEG    16
#define SEGLEN  128

static __device__ __forceinline__ u16 f2bf(float f){
  union { float f; uint32_t u; } v; v.f = f;
  uint32_t r = v.u + 0x7fffu + ((v.u >> 16) & 1u);
  return (u16)(r >> 16);
}
static __device__ __forceinline__ float bf2f(u16 h){
  union { uint32_t u; float f; } v; v.u = ((uint32_t)h) << 16;
  return v.f;
}
static __device__ __forceinline__ uint32_t packbf2(float a, float b){
  return (uint32_t)f2bf(a) | ((uint32_t)f2bf(b) << 16);
}

// ------------------------------ cast kernels -------------------------------
__global__ void k_cast_split(const float* __restrict__ x, u16* __restrict__ hi,
                             u16* __restrict__ lo, int n4){
  int i = blockIdx.x*256 + threadIdx.x;
  if (i >= n4) return;
  float4 v = reinterpret_cast<const float4*>(x)[i];
  float vs[4] = {v.x, v.y, v.z, v.w};
  union { u16 s[4]; uint2 u; } uh, ul;
#pragma unroll
  for (int r=0;r<4;++r){
    uh.s[r] = f2bf(vs[r]);
    ul.s[r] = f2bf(vs[r] - bf2f(uh.s[r]));
  }
  reinterpret_cast<uint2*>(hi)[i] = uh.u;
  reinterpret_cast<uint2*>(lo)[i] = ul.u;
}

__global__ void k_cast(const float* __restrict__ x, u16* __restrict__ hi, int n4){
  int i = blockIdx.x*256 + threadIdx.x;
  if (i >= n4) return;
  float4 v = reinterpret_cast<const float4*>(x)[i];
  float vs[4] = {v.x, v.y, v.z, v.w};
  union { u16 s[4]; uint2 u; } uh;
#pragma unroll
  for (int r=0;r<4;++r) uh.s[r] = f2bf(vs[r]);
  reinterpret_cast<uint2*>(hi)[i] = uh.u;
}

// -------------------- NT GEMM, 128x128 tile (multi-pass) -------------------
__global__ __launch_bounds__(256) void k_gemm_nt(
    const u16* A0, const u16* B0, const u16* A1, const u16* B1,
    const u16* A2, const u16* B2, int npass,
    float* __restrict__ C, int M, int N, int K)
{
  __shared__ __align__(16) u16 As[128*32];
  __shared__ __align__(16) u16 Bs[128*32];
  const int tid = threadIdx.x, wv = tid>>6, ln = tid&63;
  const int lane15 = ln&15, quad = ln>>4;
  const int wm = wv&1, wn = wv>>1;
  const size_t rowBase = (size_t)blockIdx.y*128, colBase = (size_t)blockIdx.x*128;
  f32x4 acc[4][4];
  f32x4 z = {0.f,0.f,0.f,0.f};
#pragma unroll
  for (int i=0;i<4;++i)
#pragma unroll
    for (int j=0;j<4;++j) acc[i][j] = z;
  const u16* Aps[3] = {A0, A1, A2};
  const u16* Bps[3] = {B0, B1, B2};
  const int ktiles = K >> 5;
  const int sRow = ln>>2, sCol = (ln&3)*8;
  for (int p = 0; p < npass; ++p) {
    const u16* Ap = Aps[p];
    const u16* Bp = Bps[p];
    for (int kt = 0; kt < ktiles; ++kt) {
      __syncthreads();
#pragma unroll
      for (int c = 0; c < 2; ++c) {
        int chunk = wv*2 + c;
        int r = chunk*16 + sRow;
        const u16* ga = Ap + (rowBase + r)*K + kt*32 + sCol;
        const u16* gb = Bp + (colBase + r)*K + kt*32 + sCol;
        __builtin_amdgcn_global_load_lds(
            (const __attribute__((address_space(1))) void*)ga,
            (__attribute__((address_space(3))) void*)(As + chunk*512), 16, 0, 0);
        __builtin_amdgcn_global_load_lds(
            (const __attribute__((address_space(1))) void*)gb,
            (__attribute__((address_space(3))) void*)(Bs + chunk*512), 16, 0, 0);
      }
      __syncthreads();
      bf16x8 af[4], bfb[4];
#pragma unroll
      for (int t=0;t<4;++t){
        af[t]  = *reinterpret_cast<const bf16x8*>(As + (wm*64 + t*16 + lane15)*32 + quad*8);
        bfb[t] = *reinterpret_cast<const bf16x8*>(Bs + (wn*64 + t*16 + lane15)*32 + quad*8);
      }
#pragma unroll
      for (int i=0;i<4;++i)
#pragma unroll
        for (int j=0;j<4;++j)
          acc[i][j] = __builtin_amdgcn_mfma_f32_16x16x32_bf16(af[i], bfb[j], acc[i][j], 0,0,0);
    }
  }
#pragma unroll
  for (int i=0;i<4;++i){
    size_t row = rowBase + wm*64 + i*16 + quad*4;
#pragma unroll
    for (int j=0;j<4;++j){
      size_t col = colBase + wn*64 + j*16 + lane15;
#pragma unroll
      for (int r=0;r<4;++r)
        C[(row+r)*N + col] = acc[i][j][r];
    }
  }
}

// -------------------- NT GEMM, 128x64 tile (1-pass) ------------------------
__global__ __launch_bounds__(256) void k_gemm_nt64(
    const u16* __restrict__ A0, const u16* __restrict__ B0,
    float* __restrict__ C, int M, int N, int K)
{
  __shared__ __align__(16) u16 As[128*32];
  __shared__ __align__(16) u16 Bs[64*32];
  const int tid = threadIdx.x, wv = tid>>6, ln = tid&63;
  const int lane15 = ln&15, quad = ln>>4;
  const int wm = wv&1, wn = wv>>1;
  const size_t rowBase = (size_t)blockIdx.y*128, colBase = (size_t)blockIdx.x*64;
  f32x4 acc[4][2];
  f32x4 z = {0.f,0.f,0.f,0.f};
#pragma unroll
  for (int i=0;i<4;++i){ acc[i][0] = z; acc[i][1] = z; }
  const int ktiles = K >> 5;
  const int sRow = ln>>2, sCol = (ln&3)*8;
  for (int kt = 0; kt < ktiles; ++kt) {
    __syncthreads();
#pragma unroll
    for (int c = 0; c < 2; ++c) {
      int chunk = wv*2 + c;
      int r = chunk*16 + sRow;
      const u16* ga = A0 + (rowBase + r)*K + kt*32 + sCol;
      __builtin_amdgcn_global_load_lds(
          (const __attribute__((address_space(1))) void*)ga,
          (__attribute__((address_space(3))) void*)(As + chunk*512), 16, 0, 0);
    }
    {
      int r = wv*16 + sRow;
      const u16* gb = B0 + (colBase + r)*K + kt*32 + sCol;
      __builtin_amdgcn_global_load_lds(
          (const __attribute__((address_space(1))) void*)gb,
          (__attribute__((address_space(3))) void*)(Bs + wv*512), 16, 0, 0);
    }
    __syncthreads();
    bf16x8 af[4], bfb[2];
#pragma unroll
    for (int t=0;t<4;++t)
      af[t]  = *reinterpret_cast<const bf16x8*>(As + (wm*64 + t*16 + lane15)*32 + quad*8);
#pragma unroll
    for (int t=0;t<2;++t)
      bfb[t] = *reinterpret_cast<const bf16x8*>(Bs + (wn*32 + t*16 + lane15)*32 + quad*8);
#pragma unroll
    for (int i=0;i<4;++i)
#pragma unroll
      for (int j=0;j<2;++j)
        acc[i][j] = __builtin_amdgcn_mfma_f32_16x16x32_bf16(af[i], bfb[j], acc[i][j], 0,0,0);
  }
#pragma unroll
  for (int i=0;i<4;++i){
    size_t row = rowBase + wm*64 + i*16 + quad*4;
#pragma unroll
    for (int j=0;j<2;++j){
      size_t col = colBase + wn*32 + j*16 + lane15;
#pragma unroll
      for (int r=0;r<4;++r)
        C[(row+r)*N + col] = acc[i][j][r];
    }
  }
}

// ----------------- head-0 scores + fused segment column sums ---------------
__global__ __launch_bounds__(256) void k_s0(
    const u16* Qh, const u16* Q0l, const u16* Kh, const u16* K0l,
    float* __restrict__ S0, float* __restrict__ seg)
{
  const int b = blockIdx.z;
  const int bm = blockIdx.y;  // j (query-row) tile == segment index
  const int bn = blockIdx.x;  // m (key-col) tile
  float* Sb = S0 + (size_t)b*SEQ*SEQ;
  const int tid = threadIdx.x;
  if (bn > bm){               // fully above diagonal -> zeros
    float4 zz = {0.f,0.f,0.f,0.f};
    for (int t = tid; t < 128*32; t += 256){
      int r = t >> 5, c = t & 31;
      reinterpret_cast<float4*>(Sb + (size_t)(bm*128 + r)*SEQ + bn*128)[c] = zz;
    }
    if (tid < 128) seg[((size_t)b*NSEG + bm)*SEQ + bn*128 + tid] = 0.f;
    return;
  }
  __shared__ __align__(16) u16 As[128*32];
  __shared__ __align__(16) u16 Bs[128*32];
  __shared__ float cs[2][128];
  const int wv = tid>>6, ln = tid&63;
  const int lane15 = ln&15, quad = ln>>4;
  const int wm = wv&1, wn = wv>>1;
  f32x4 acc[4][4];
  f32x4 z = {0.f,0.f,0.f,0.f};
#pragma unroll
  for (int i=0;i<4;++i)
#pragma unroll
    for (int j=0;j<4;++j) acc[i][j] = z;
  const u16* Qb  = Qh  + (size_t)b*N_HEADS*SEQ*D_HEAD;   // head 0
  const u16* Kb  = Kh  + (size_t)b*N_HEADS*SEQ*D_HEAD;
  const u16* Qlb = Q0l + (size_t)b*SEQ*D_HEAD;
  const u16* Klb = K0l + (size_t)b*SEQ*D_HEAD;
  const u16* Aps[3] = {Qb, Qb, Qlb};
  const u16* Bps[3] = {Kb, Klb, Kb};
  const int sRow = ln>>2, sCol = (ln&3)*8;
  const size_t rowBase = (size_t)bm*128, colBase = (size_t)bn*128;
  for (int p = 0; p < 3; ++p) {
    const u16* Ap = Aps[p];
    const u16* Bp = Bps[p];
    for (int kt = 0; kt < 2; ++kt) {
      __syncthreads();
#pragma unroll
      for (int c = 0; c < 2; ++c) {
        int chunk = wv*2 + c;
        int r = chunk*16 + sRow;
        const u16* ga = Ap + (rowBase + r)*D_HEAD + kt*32 + sCol;
        const u16* gb = Bp + (colBase + r)*D_HEAD + kt*32 + sCol;
        __builtin_amdgcn_global_load_lds(
            (const __attribute__((address_space(1))) void*)ga,
            (__attribute__((address_space(3))) void*)(As + chunk*512), 16, 0, 0);
        __builtin_amdgcn_global_load_lds(
            (const __attribute__((address_space(1))) void*)gb,
            (__attribute__((address_space(3))) void*)(Bs + chunk*512), 16, 0, 0);
      }
      __syncthreads();
      bf16x8 af[4], bfb[4];
#pragma unroll
      for (int t=0;t<4;++t){
        af[t]  = *reinterpret_cast<const bf16x8*>(As + (wm*64 + t*16 + lane15)*32 + quad*8);
        bfb[t] = *reinterpret_cast<const bf16x8*>(Bs + (wn*64 + t*16 + lane15)*32 + quad*8);
      }
#pragma unroll
      for (int i=0;i<4;++i)
#pragma unroll
        for (int j=0;j<4;++j)
          acc[i][j] = __builtin_amdgcn_mfma_f32_16x16x32_bf16(af[i], bfb[j], acc[i][j], 0,0,0);
    }
  }
  float csum[4] = {0.f,0.f,0.f,0.f};
#pragma unroll
  for (int i=0;i<4;++i){
#pragma unroll
    for (int j=0;j<4;++j){
#pragma unroll
      for (int r=0;r<4;++r){
        int jg = (int)rowBase + wm*64 + i*16 + quad*4 + r;
        int mg = (int)colBase + wn*64 + j*16 + lane15;
        float l = acc[i][j][r]*0.125f;
        float s = (mg >= 1 && mg < jg) ? fmaxf(l, 0.f) : 0.f;
        Sb[(size_t)jg*SEQ + mg] = s;
        csum[j] += s;
      }
    }
  }
#pragma unroll
  for (int j=0;j<4;++j){
    float v = csum[j];
    v += __shfl_xor(v, 16);
    v += __shfl_xor(v, 32);
    if (ln < 16) cs[wm][wn*64 + j*16 + ln] = v;
  }
  __syncthreads();
  if (tid < 128)
    seg[((size_t)b*NSEG + bm)*SEQ + bn*128 + tid] = cs[0][tid] + cs[1][tid];
}

// -------------------- LN + pack to bf16 head layout ------------------------
__global__ __launch_bounds__(256) void k_ln_pack(
    const float* __restrict__ Xp, int ld, const float* __restrict__ g,
    const float* __restrict__ bb, u16* __restrict__ Oh, u16* __restrict__ Olo)
{
  const int row = blockIdx.x;
  const int tid = threadIdx.x;
  const float* xr = Xp + (size_t)row*ld;
  float4 v = reinterpret_cast<const float4*>(xr)[tid];
  float s  = v.x+v.y+v.z+v.w;
  float s2 = v.x*v.x+v.y*v.y+v.z*v.z+v.w*v.w;
#pragma unroll
  for (int o=32;o;o>>=1){ s += __shfl_xor(s,o); s2 += __shfl_xor(s2,o); }
  __shared__ float ps[4], ps2[4];
  if ((tid&63)==0){ ps[tid>>6]=s; ps2[tid>>6]=s2; }
  __syncthreads();
  s  = ps[0]+ps[1]+ps[2]+ps[3];
  s2 = ps2[0]+ps2[1]+ps2[2]+ps2[3];
  const float mu  = s*(1.f/D_MODEL);
  const float var = s2*(1.f/D_MODEL) - mu*mu;
  const float rs  = rsqrtf(var + 1e-5f);
  const int b = row >> 11, n = row & (SEQ-1);
  const int j0 = tid*4, h = j0 >> 6, d0 = j0 & 63;
  float4 gv = reinterpret_cast<const float4*>(g)[tid];
  float4 bv = reinterpret_cast<const float4*>(bb)[tid];
  float xs[4] = {v.x,v.y,v.z,v.w};
  float gs[4] = {gv.x,gv.y,gv.z,gv.w};
  float bs[4] = {bv.x,bv.y,bv.z,bv.w};
  union { u16 s[4]; uint2 u; } uh, ul;
#pragma unroll
  for (int r=0;r<4;++r){
    float y = (xs[r]-mu)*rs*gs[r] + bs[r];
    uh.s[r] = f2bf(y);
    ul.s[r] = f2bf(y - bf2f(uh.s[r]));
  }
  u16* dst = Oh + (((size_t)(b*N_HEADS + h))*SEQ + n)*D_HEAD + d0;
  *reinterpret_cast<uint2*>(dst) = uh.u;
  if (h == 0){
    u16* dl = Olo + ((size_t)b*SEQ + n)*D_HEAD + d0;
    *reinterpret_cast<uint2*>(dl) = ul.u;
  }
}

// ------------------------- V -> V^T bf16 (b,h,d,n) -------------------------
__global__ void k_vt_pack(const float* __restrict__ XV, u16* __restrict__ Vt){
  int t = blockIdx.x*256 + threadIdx.x;
  int d  = t & 63;
  int c  = (t >> 6) & 255;
  int bh = t >> 14;
  int b = bh >> 4, h = bh & 15;
  int n0 = c*8;
  union { u16 s[8]; uint4 u; } o;
#pragma unroll
  for (int i=0;i<8;++i)
    o.s[i] = f2bf(XV[((size_t)(b*SEQ + n0 + i))*D_MODEL + h*64 + d]);
  *reinterpret_cast<uint4*>(Vt + ((size_t)bh*D_HEAD + d)*SEQ + n0) = o.u;
}

// -------------------- segmented exclusive cumsum over n --------------------
__global__ void k_seg_scan(float* __restrict__ seg){
  int m = blockIdx.x*256 + threadIdx.x;
  int b = blockIdx.y;
  float run = 0.f;
#pragma unroll
  for (int s=0;s<NSEG;++s){
    size_t idx = ((size_t)b*NSEG + s)*SEQ + m;
    float t = seg[idx]; seg[idx] = run; run += t;
  }
}
__global__ void k_seg_apply(float* __restrict__ SF, const float* __restrict__ seg){
  int m = blockIdx.x*256 + threadIdx.x;
  int s = blockIdx.y, b = blockIdx.z;
  float run = seg[((size_t)b*NSEG + s)*SEQ + m];
  float* Sb = SF + (size_t)b*SEQ*SEQ;
  for (int i=0;i<SEGLEN;++i){
    size_t idx = (size_t)(s*SEGLEN + i)*SEQ + m;
    float t = Sb[idx]; Sb[idx] = run; run += t;
  }
}

// ----------------------- flash attention with F-mask -----------------------
// 64-row Q tile per block (wave -> 16 rows), 64-col K/V chunks.
__global__ __launch_bounds__(256, 4) void k_attn(
    const u16* __restrict__ Qh, const u16* __restrict__ Kh,
    const u16* __restrict__ Vt, const float* __restrict__ F,
    u16* __restrict__ Ob)
{
  __shared__ __align__(16) u16 Ks[64*64];
  __shared__ __align__(16) u16 Vs[64*64];
  __shared__ float alphas[64];
  __shared__ float lsums[64];
  const int h = blockIdx.x, b = blockIdx.z;
  const int nt = b ? (int)(gridDim.y - 1 - blockIdx.y) : (int)blockIdx.y;
  const int tid = threadIdx.x, wv = tid>>6, ln = tid&63;
  const int lane15 = ln&15, quad = ln>>4;
  const u16* Qbh = Qh + ((size_t)(b*N_HEADS + h))*SEQ*D_HEAD;
  const u16* Kbh = Kh + ((size_t)(b*N_HEADS + h))*SEQ*D_HEAD;
  const u16* Vbh = Vt + ((size_t)(b*N_HEADS + h))*D_HEAD*SEQ;
  const float* Fb = F + (size_t)b*SEQ*SEQ;
  const int n_loc = wv*16 + lane15;
  const int n_g = nt*64 + n_loc;
  const int swz = (ln&7) ^ ((ln>>3)&7);           // staging swizzle
  const int fswz = lane15 & 7;                    // fragment-read swizzle key

  bf16x8 qf[2];
#pragma unroll
  for (int kt=0; kt<2; ++kt)
    qf[kt] = *reinterpret_cast<const bf16x8*>(Qbh + (size_t)n_g*D_HEAD + kt*32 + quad*8);

  float m_run = -1e30f, l_run = 0.f;
  f32x4 acc_o[4];
  f32x4 z = {0.f,0.f,0.f,0.f};
#pragma unroll
  for (int no=0;no<4;++no) acc_o[no] = z;

  for (int mt = 0; mt <= nt; ++mt) {
    __syncthreads();
#pragma unroll
    for (int c=0;c<2;++c){
      int chunk = wv*2 + c;
      int r = chunk*8 + (ln>>3);
      const u16* gk = Kbh + (size_t)(mt*64 + r)*D_HEAD + swz*8;
      const u16* gv = Vbh + (size_t)r*SEQ + mt*64 + swz*8;
      __builtin_amdgcn_global_load_lds(
          (const __attribute__((address_space(1))) void*)gk,
          (__attribute__((address_space(3))) void*)(Ks + chunk*512), 16, 0, 0);
      __builtin_amdgcn_global_load_lds(
          (const __attribute__((address_space(1))) void*)gv,
          (__attribute__((address_space(3))) void*)(Vs + chunk*512), 16, 0, 0);
    }
    __syncthreads();

    // S^T chunk: rows m (4 x 16), col n = lane15
    f32x4 accs[4];
#pragma unroll
    for (int ms=0;ms<4;++ms) accs[ms] = z;
#pragma unroll
    for (int kt=0; kt<2; ++kt){
#pragma unroll
      for (int ms=0; ms<4; ++ms){
        bf16x8 a = *reinterpret_cast<const bf16x8*>(
            Ks + (ms*16 + lane15)*64 + (((kt*4 + quad) ^ fswz) * 8));
        accs[ms] = __builtin_amdgcn_mfma_f32_16x16x32_bf16(a, qf[kt], accs[ms], 0,0,0);
      }
    }
    // softmax (each lane owns full row n_g for its 16 m-values)
    const float* Fr = Fb + (size_t)n_g*SEQ + mt*64;
    float mx = -1e30f;
#pragma unroll
    for (int ms=0; ms<4; ++ms){
      f32x4 fv = *reinterpret_cast<const f32x4*>(Fr + ms*16 + quad*4);
      f32x4 t = accs[ms];
#pragma unroll
      for (int r=0;r<4;++r){
        int m_g = mt*64 + ms*16 + quad*4 + r;
        float l = t[r]*0.125f - fv[r];
        l = (m_g > n_g) ? -1e30f : l;
        t[r] = l;
        mx = fmaxf(mx, l);
      }
      accs[ms] = t;
    }
    mx = fmaxf(mx, __shfl_xor(mx, 16));
    mx = fmaxf(mx, __shfl_xor(mx, 32));
    float mnew = fmaxf(m_run, mx);
    float alpha = __expf(m_run - mnew);
    float psum = 0.f;
    uint32_t pw[4][2];
#pragma unroll
    for (int ms=0; ms<4; ++ms){
      f32x4 t = accs[ms];
      float p0 = __expf(t[0]-mnew), p1 = __expf(t[1]-mnew);
      float p2 = __expf(t[2]-mnew), p3 = __expf(t[3]-mnew);
      psum += (p0+p1)+(p2+p3);
      pw[ms][0] = packbf2(p0,p1);
      pw[ms][1] = packbf2(p2,p3);
    }
    psum += __shfl_xor(psum, 16);
    psum += __shfl_xor(psum, 32);
    l_run = l_run*alpha + psum;
    m_run = mnew;
    if (ln < 16) alphas[wv*16 + ln] = alpha;
    // rescale O accumulator (rows are quad*4+r within wave's 16)
    f32x4 al = *reinterpret_cast<const f32x4*>(&alphas[wv*16 + quad*4]);
#pragma unroll
    for (int no=0;no<4;++no) acc_o[no] *= al;
    // P relayout: (m=quad*4+r) -> A-fragment (k=quad*8+j) via quad shuffles
#pragma unroll
    for (int kt=0; kt<2; ++kt){
      union { uint32_t u[4]; bf16x8 v; } pa;
#pragma unroll
      for (int w=0; w<4; ++w){
        int sl = lane15 + 16*((quad&1)*2 + (w>>1));
        uint32_t t0 = (uint32_t)__shfl((int)pw[2*kt  ][w&1], sl);
        uint32_t t1 = (uint32_t)__shfl((int)pw[2*kt+1][w&1], sl);
        pa.u[w] = (quad < 2) ? t0 : t1;
      }
#pragma unroll
      for (int no=0; no<4; ++no){
        int d = no*16 + lane15;
        bf16x8 vb = *reinterpret_cast<const bf16x8*>(
            Vs + d*64 + (((kt*4 + quad) ^ (d&7)) * 8));
        acc_o[no] = __builtin_amdgcn_mfma_f32_16x16x32_bf16(pa.v, vb, acc_o[no], 0,0,0);
      }
    }
  }
  if (ln < 16) lsums[wv*16 + ln] = l_run;
  f32x4 ls = *reinterpret_cast<const f32x4*>(&lsums[wv*16 + quad*4]);
#pragma unroll
  for (int no=0; no<4; ++no){
#pragma unroll
    for (int r=0;r<4;++r){
      float o = acc_o[no][r] / ls[r];
      int row = nt*64 + wv*16 + quad*4 + r;
      Ob[((size_t)(b*SEQ + row))*D_MODEL + h*64 + no*16 + lane15] = f2bf(o);
    }
  }
}

// ------------------------------- launcher ----------------------------------
extern "C" void kernel_launch(void* const* d_in, const int* in_sizes, int n_in,
                              void* d_out, int out_size, void* d_ws, size_t ws_size,
                              hipStream_t stream)
{
  (void)in_sizes; (void)n_in; (void)out_size; (void)ws_size;
  const float* X  = (const float*)d_in[0];
  const float* Wq = (const float*)d_in[1];
  const float* Wk = (const float*)d_in[2];
  const float* Wv = (const float*)d_in[3];
  const float* Wo = (const float*)d_in[4];
  const float* gq = (const float*)d_in[5];
  const float* bq = (const float*)d_in[6];
  const float* gk = (const float*)d_in[7];
  const float* bk = (const float*)d_in[8];
  float* out = (float*)d_out;

  char* ws = (char*)d_ws;
  size_t off = 0;
  auto alloc = [&](size_t bytes)->char*{
    char* p = ws + off; off += (bytes + 255) & ~(size_t)255; return p;
  };
  u16* Xhi  = (u16*)alloc((size_t)ROWS*D_MODEL*2);
  u16* Xlo  = (u16*)alloc((size_t)ROWS*D_MODEL*2);
  u16* Wqkh = (u16*)alloc((size_t)2*D_MODEL*D_MODEL*2);  // [Wq;Wk] hi
  u16* Wqkl = (u16*)alloc((size_t)2*D_MODEL*D_MODEL*2);  // [Wq;Wk] lo
  u16* Wvb  = (u16*)alloc((size_t)D_MODEL*D_MODEL*2);
  u16* Wob  = (u16*)alloc((size_t)D_MODEL*D_MODEL*2);
  u16* Qhp  = (u16*)alloc((size_t)BATCH*N_HEADS*SEQ*D_HEAD*2);
  u16* Khp  = (u16*)alloc((size_t)BATCH*N_HEADS*SEQ*D_HEAD*2);
  u16* Q0l  = (u16*)alloc((size_t)BATCH*SEQ*D_HEAD*2);
  u16* K0l  = (u16*)alloc((size_t)BATCH*SEQ*D_HEAD*2);
  u16* Vtp  = (u16*)alloc((size_t)BATCH*N_HEADS*D_HEAD*SEQ*2);
  u16* Obf  = (u16*)alloc((size_t)ROWS*D_MODEL*2);
  float* Seg = (float*)alloc((size_t)BATCH*NSEG*SEQ*4);
  float* SF  = (float*)alloc((size_t)BATCH*SEQ*SEQ*4);   // 33.5 MB
  float* C32 = SF;          // QK-proj fp32 scratch aliases SF (consumed first)
  float* V32 = out;         // V-proj fp32 scratch in d_out (consumed first)

  const int nX4 = ROWS*D_MODEL/4, nW4 = D_MODEL*D_MODEL/4;
  k_cast_split<<<(nX4+255)/256, 256, 0, stream>>>(X, Xhi, Xlo, nX4);
  k_cast_split<<<(nW4+255)/256, 256, 0, stream>>>(Wq, Wqkh, Wqkl, nW4);
  k_cast_split<<<(nW4+255)/256, 256, 0, stream>>>(Wk, Wqkh + (size_t)D_MODEL*D_MODEL,
                                                  Wqkl + (size_t)D_MODEL*D_MODEL, nW4);
  k_cast<<<(nW4+255)/256, 256, 0, stream>>>(Wv, Wvb, nW4);
  k_cast<<<(nW4+255)/256, 256, 0, stream>>>(Wo, Wob, nW4);

  // merged Q+K projection (3-pass split), N=2048
  k_gemm_nt<<<dim3(2*D_MODEL/128, ROWS/128), 256, 0, stream>>>(
      Xhi, Wqkh, Xhi, Wqkl, Xlo, Wqkh, 3, C32, ROWS, 2*D_MODEL, D_MODEL);
  k_ln_pack<<<ROWS, 256, 0, stream>>>(C32,           2*D_MODEL, gq, bq, Qhp, Q0l);
  k_ln_pack<<<ROWS, 256, 0, stream>>>(C32 + D_MODEL, 2*D_MODEL, gk, bk, Khp, K0l);
  // V projection (1-pass, 128x64 tiles) + transpose-pack
  k_gemm_nt64<<<dim3(D_MODEL/64, ROWS/128), 256, 0, stream>>>(
      Xhi, Wvb, V32, ROWS, D_MODEL, D_MODEL);
  k_vt_pack<<<BATCH*N_HEADS*64, 256, 0, stream>>>(V32, Vtp);
  // head-0 scores + fused segment sums; then scan + apply (F in place on SF)
  k_s0<<<dim3(SEQ/128, SEQ/128, BATCH), 256, 0, stream>>>(Qhp, Q0l, Khp, K0l, SF, Seg);
  k_seg_scan<<<dim3(SEQ/256, BATCH), 256, 0, stream>>>(Seg);
  k_seg_apply<<<dim3(SEQ/256, NSEG, BATCH), 256, 0, stream>>>(SF, Seg);
  // attention (64-row Q tiles)
  k_attn<<<dim3(N_HEADS, SEQ/64, BATCH), 256, 0, stream>>>(Qhp, Khp, Vtp, SF, Obf);
  // output projection (1-pass, 128x64 tiles)
  k_gemm_nt64<<<dim3(D_MODEL/64, ROWS/128), 256, 0, stream>>>(
      Obf, Wob, out, ROWS, D_MODEL, D_MODEL);
}

// Round 3
// 331.416 us; speedup vs baseline: 1.4229x; 1.0988x over previous
//
#include <hip/hip_runtime.h>
#include <cstdint>
#include <cstddef>

// ---------------------------------------------------------------------------
// MultiheadSelectiveAttention (B=2, S=2048, D=1024, H=16, dh=64), fp32 in/out.
//   k_cast_split_all: X,Wq,Wk -> hi/lo bf16 ; k_cast2: Wv,Wo -> bf16
//   k_gemm_qk: [XQ|XK] = X@[Wq;Wk]^T, 1-pass except head0 col-tiles (3-pass)
//   k_ln_pack2: both LNs from one C32 read -> Q/K bf16 packs (+head0 lo)
//   k_gemm_vt: XV GEMM with fused V^T bf16 epilogue (LDS transpose)
//   k_s0: head-0 scores (3-pass split) + fused segment column sums
//   k_seg_scan / k_seg_apply: exclusive cumsum; apply stores -F*log2e
//   k_attn: fixed-max flash attention (F[:,0]==0 => row max in [-8,8]),
//           double-buffered DMA staging, register P via quad shuffles
//   k_gemm_nt64: out = Obf @ Wo^T
// ---------------------------------------------------------------------------

typedef unsigned short u16;
typedef __attribute__((ext_vector_type(8))) __bf16 bf16x8;
typedef __attribute__((ext_vector_type(4))) float f32x4;

#define D_MODEL 1024
#define N_HEADS 16
#define BATCH   2
#define SEQ     2048
#define D_HEAD  64
#define ROWS    (BATCH*SEQ)   /* 4096 */
#define NSEG    16
#define SEGLEN  128
#define LOG2E   1.44269504f

static __device__ __forceinline__ u16 f2bf(float f){
  union { float f; uint32_t u; } v; v.f = f;
  uint32_t r = v.u + 0x7fffu + ((v.u >> 16) & 1u);
  return (u16)(r >> 16);
}
static __device__ __forceinline__ float bf2f(u16 h){
  union { uint32_t u; float f; } v; v.u = ((uint32_t)h) << 16;
  return v.f;
}
// round-half-up bf16 pair pack (cheap: 2 adds + merge)
static __device__ __forceinline__ uint32_t pack2(float a, float b){
  uint32_t ua = __float_as_uint(a) + 0x8000u;
  uint32_t ub = __float_as_uint(b) + 0x8000u;
  return (ua >> 16) | (ub & 0xffff0000u);
}

// ------------------------------ cast kernels -------------------------------
__global__ void k_cast_split_all(const float* __restrict__ X,
                                 u16* __restrict__ Xhi, u16* __restrict__ Xlo,
                                 const float* __restrict__ Wq,
                                 u16* __restrict__ Wqh, u16* __restrict__ Wql,
                                 const float* __restrict__ Wk,
                                 u16* __restrict__ Wkh, u16* __restrict__ Wkl){
  int i = blockIdx.x*256 + threadIdx.x;   // float4 index over 1.5M
  const float* src; u16 *dh, *dl; int base;
  if (i < 1048576){ src = X;  dh = Xhi; dl = Xlo; base = i; }
  else if (i < 1310720){ src = Wq; dh = Wqh; dl = Wql; base = i - 1048576; }
  else { src = Wk; dh = Wkh; dl = Wkl; base = i - 1310720; }
  float4 v = reinterpret_cast<const float4*>(src)[base];
  float vs[4] = {v.x, v.y, v.z, v.w};
  union { u16 s[4]; uint2 u; } uh, ul;
#pragma unroll
  for (int r=0;r<4;++r){
    uh.s[r] = f2bf(vs[r]);
    ul.s[r] = f2bf(vs[r] - bf2f(uh.s[r]));
  }
  reinterpret_cast<uint2*>(dh)[base] = uh.u;
  reinterpret_cast<uint2*>(dl)[base] = ul.u;
}

__global__ void k_cast2(const float* __restrict__ Wv, u16* __restrict__ Wvb,
                        const float* __restrict__ Wo, u16* __restrict__ Wob){
  int i = blockIdx.x*256 + threadIdx.x;   // float4 index over 512K
  const float* src; u16* dst; int base;
  if (i < 262144){ src = Wv; dst = Wvb; base = i; }
  else { src = Wo; dst = Wob; base = i - 262144; }
  float4 v = reinterpret_cast<const float4*>(src)[base];
  float vs[4] = {v.x, v.y, v.z, v.w};
  union { u16 s[4]; uint2 u; } uh;
#pragma unroll
  for (int r=0;r<4;++r) uh.s[r] = f2bf(vs[r]);
  reinterpret_cast<uint2*>(dst)[base] = uh.u;
}

// ----------- QK projection: 1-pass, except head0 col-tiles 3-pass ----------
__global__ __launch_bounds__(256) void k_gemm_qk(
    const u16* __restrict__ Xhi, const u16* __restrict__ Xlo,
    const u16* __restrict__ Wh, const u16* __restrict__ Wl,
    float* __restrict__ C)
{
  __shared__ __align__(16) u16 As[128*32];
  __shared__ __align__(16) u16 Bs[128*32];
  const int tid = threadIdx.x, wv = tid>>6, ln = tid&63;
  const int lane15 = ln&15, quad = ln>>4;
  const int wm = wv&1, wn = wv>>1;
  const size_t rowBase = (size_t)blockIdx.y*128, colBase = (size_t)blockIdx.x*128;
  const int npass = ((blockIdx.x & 7) == 0) ? 3 : 1;  // cols 0-127 / 1024-1151
  f32x4 acc[4][4];
  f32x4 z = {0.f,0.f,0.f,0.f};
#pragma unroll
  for (int i=0;i<4;++i)
#pragma unroll
    for (int j=0;j<4;++j) acc[i][j] = z;
  const u16* Aps[3] = {Xhi, Xhi, Xlo};
  const u16* Bps[3] = {Wh, Wl, Wh};
  const int sRow = ln>>2, sCol = (ln&3)*8;
  for (int p = 0; p < npass; ++p) {
    const u16* Ap = Aps[p];
    const u16* Bp = Bps[p];
    for (int kt = 0; kt < 32; ++kt) {
      __syncthreads();
#pragma unroll
      for (int c = 0; c < 2; ++c) {
        int chunk = wv*2 + c;
        int r = chunk*16 + sRow;
        const u16* ga = Ap + (rowBase + r)*1024 + kt*32 + sCol;
        const u16* gb = Bp + (colBase + r)*1024 + kt*32 + sCol;
        __builtin_amdgcn_global_load_lds(
            (const __attribute__((address_space(1))) void*)ga,
            (__attribute__((address_space(3))) void*)(As + chunk*512), 16, 0, 0);
        __builtin_amdgcn_global_load_lds(
            (const __attribute__((address_space(1))) void*)gb,
            (__attribute__((address_space(3))) void*)(Bs + chunk*512), 16, 0, 0);
      }
      __syncthreads();
      bf16x8 af[4], bfb[4];
#pragma unroll
      for (int t=0;t<4;++t){
        af[t]  = *reinterpret_cast<const bf16x8*>(As + (wm*64 + t*16 + lane15)*32 + quad*8);
        bfb[t] = *reinterpret_cast<const bf16x8*>(Bs + (wn*64 + t*16 + lane15)*32 + quad*8);
      }
#pragma unroll
      for (int i=0;i<4;++i)
#pragma unroll
        for (int j=0;j<4;++j)
          acc[i][j] = __builtin_amdgcn_mfma_f32_16x16x32_bf16(af[i], bfb[j], acc[i][j], 0,0,0);
    }
  }
#pragma unroll
  for (int i=0;i<4;++i){
    size_t row = rowBase + wm*64 + i*16 + quad*4;
#pragma unroll
    for (int j=0;j<4;++j){
      size_t col = colBase + wn*64 + j*16 + lane15;
#pragma unroll
      for (int r=0;r<4;++r)
        C[(row+r)*2048 + col] = acc[i][j][r];
    }
  }
}

// --------- merged LN for Q and K + bf16 head packs (+ head0 lo) ------------
__global__ __launch_bounds__(256) void k_ln_pack2(
    const float* __restrict__ C,
    const float* __restrict__ gq, const float* __restrict__ bq,
    const float* __restrict__ gk, const float* __restrict__ bk,
    u16* __restrict__ Qh, u16* __restrict__ Kh,
    u16* __restrict__ Q0l, u16* __restrict__ K0l)
{
  const int row = blockIdx.x;
  const int tid = threadIdx.x;
  const float* cr = C + (size_t)row*2048;
  float4 vq = reinterpret_cast<const float4*>(cr)[tid];
  float4 vk = reinterpret_cast<const float4*>(cr)[256 + tid];
  float sq  = vq.x+vq.y+vq.z+vq.w;
  float s2q = vq.x*vq.x+vq.y*vq.y+vq.z*vq.z+vq.w*vq.w;
  float sk  = vk.x+vk.y+vk.z+vk.w;
  float s2k = vk.x*vk.x+vk.y*vk.y+vk.z*vk.z+vk.w*vk.w;
#pragma unroll
  for (int o=32;o;o>>=1){
    sq += __shfl_xor(sq,o);  s2q += __shfl_xor(s2q,o);
    sk += __shfl_xor(sk,o);  s2k += __shfl_xor(s2k,o);
  }
  __shared__ float red[4][4];
  if ((tid&63)==0){
    red[tid>>6][0]=sq; red[tid>>6][1]=s2q; red[tid>>6][2]=sk; red[tid>>6][3]=s2k;
  }
  __syncthreads();
  sq  = red[0][0]+red[1][0]+red[2][0]+red[3][0];
  s2q = red[0][1]+red[1][1]+red[2][1]+red[3][1];
  sk  = red[0][2]+red[1][2]+red[2][2]+red[3][2];
  s2k = red[0][3]+red[1][3]+red[2][3]+red[3][3];
  const float muq = sq*(1.f/D_MODEL);
  const float rsq = rsqrtf(s2q*(1.f/D_MODEL) - muq*muq + 1e-5f);
  const float muk = sk*(1.f/D_MODEL);
  const float rsk = rsqrtf(s2k*(1.f/D_MODEL) - muk*muk + 1e-5f);
  const int b = row >> 11, n = row & (SEQ-1);
  const int h = tid >> 4, d0 = (tid & 15)*4;
  float4 gqv = reinterpret_cast<const float4*>(gq)[tid];
  float4 bqv = reinterpret_cast<const float4*>(bq)[tid];
  float4 gkv = reinterpret_cast<const float4*>(gk)[tid];
  float4 bkv = reinterpret_cast<const float4*>(bk)[tid];
  float xq[4] = {vq.x,vq.y,vq.z,vq.w}, xk[4] = {vk.x,vk.y,vk.z,vk.w};
  float gQ[4] = {gqv.x,gqv.y,gqv.z,gqv.w}, bQ[4] = {bqv.x,bqv.y,bqv.z,bqv.w};
  float gK[4] = {gkv.x,gkv.y,gkv.z,gkv.w}, bK[4] = {bkv.x,bkv.y,bkv.z,bkv.w};
  union { u16 s[4]; uint2 u; } qh, ql, kh, kl;
#pragma unroll
  for (int r=0;r<4;++r){
    float yq = (xq[r]-muq)*rsq*gQ[r] + bQ[r];
    qh.s[r] = f2bf(yq);
    ql.s[r] = f2bf(yq - bf2f(qh.s[r]));
    float yk = (xk[r]-muk)*rsk*gK[r] + bK[r];
    kh.s[r] = f2bf(yk);
    kl.s[r] = f2bf(yk - bf2f(kh.s[r]));
  }
  size_t dst = (((size_t)(b*N_HEADS + h))*SEQ + n)*D_HEAD + d0;
  *reinterpret_cast<uint2*>(Qh + dst) = qh.u;
  *reinterpret_cast<uint2*>(Kh + dst) = kh.u;
  if (h == 0){
    size_t dl = ((size_t)b*SEQ + n)*D_HEAD + d0;
    *reinterpret_cast<uint2*>(Q0l + dl) = ql.u;
    *reinterpret_cast<uint2*>(K0l + dl) = kl.u;
  }
}

// --------- V projection with fused V^T bf16 epilogue (LDS transpose) -------
__global__ __launch_bounds__(256) void k_gemm_vt(
    const u16* __restrict__ A0, const u16* __restrict__ B0,
    u16* __restrict__ Vt)
{
  __shared__ __align__(16) u16 smem[64*136];   // 17408 B; staging overlays
  u16* As = smem;              // 128*32
  u16* Bs = smem + 128*32;     // 64*32
  const int tid = threadIdx.x, wv = tid>>6, ln = tid&63;
  const int lane15 = ln&15, quad = ln>>4;
  const int wm = wv&1, wn = wv>>1;
  const size_t rowBase = (size_t)blockIdx.y*128, colBase = (size_t)blockIdx.x*64;
  f32x4 acc[4][2];
  f32x4 z = {0.f,0.f,0.f,0.f};
#pragma unroll
  for (int i=0;i<4;++i){ acc[i][0] = z; acc[i][1] = z; }
  const int sRow = ln>>2, sCol = (ln&3)*8;
  for (int kt = 0; kt < 32; ++kt) {
    __syncthreads();
#pragma unroll
    for (int c = 0; c < 2; ++c) {
      int chunk = wv*2 + c;
      int r = chunk*16 + sRow;
      const u16* ga = A0 + (rowBase + r)*1024 + kt*32 + sCol;
      __builtin_amdgcn_global_load_lds(
          (const __attribute__((address_space(1))) void*)ga,
          (__attribute__((address_space(3))) void*)(As + chunk*512), 16, 0, 0);
    }
    {
      int r = wv*16 + sRow;
      const u16* gb = B0 + (colBase + r)*1024 + kt*32 + sCol;
      __builtin_amdgcn_global_load_lds(
          (const __attribute__((address_space(1))) void*)gb,
          (__attribute__((address_space(3))) void*)(Bs + wv*512), 16, 0, 0);
    }
    __syncthreads();
    bf16x8 af[4], bfb[2];
#pragma unroll
    for (int t=0;t<4;++t)
      af[t]  = *reinterpret_cast<const bf16x8*>(As + (wm*64 + t*16 + lane15)*32 + quad*8);
#pragma unroll
    for (int t=0;t<2;++t)
      bfb[t] = *reinterpret_cast<const bf16x8*>(Bs + (wn*32 + t*16 + lane15)*32 + quad*8);
#pragma unroll
    for (int i=0;i<4;++i)
#pragma unroll
      for (int j=0;j<2;++j)
        acc[i][j] = __builtin_amdgcn_mfma_f32_16x16x32_bf16(af[i], bfb[j], acc[i][j], 0,0,0);
  }
  // transpose epilogue: stage bf16 tile as [d 64][n 128] (stride 136)
  __syncthreads();
#pragma unroll
  for (int i=0;i<4;++i){
    int nl = wm*64 + i*16 + quad*4;
#pragma unroll
    for (int j=0;j<2;++j){
      int dl = wn*32 + j*16 + lane15;
#pragma unroll
      for (int r=0;r<4;++r)
        smem[dl*136 + nl + r] = f2bf(acc[i][j][r]);
    }
  }
  __syncthreads();
  const int b = (int)blockIdx.y >> 4;
  const int n0 = ((int)blockIdx.y & 15) * 128;
  const int bh = b*N_HEADS + (int)blockIdx.x;
  const int d = tid >> 2, seg = tid & 3;
  u16* dst = Vt + ((size_t)(bh*64 + d))*SEQ + n0 + seg*32;
  const u16* srcl = smem + d*136 + seg*32;
#pragma unroll
  for (int k=0;k<4;++k)
    *reinterpret_cast<uint4*>(dst + k*8) = *reinterpret_cast<const uint4*>(srcl + k*8);
}

// ----------------- head-0 scores + fused segment column sums ---------------
__global__ __launch_bounds__(256) void k_s0(
    const u16* Qh, const u16* Q0l, const u16* Kh, const u16* K0l,
    float* __restrict__ S0, float* __restrict__ seg)
{
  const int b = blockIdx.z;
  const int bm = blockIdx.y;  // j (query-row) tile == segment index
  const int bn = blockIdx.x;  // m (key-col) tile
  const int tid = threadIdx.x;
  if (bn > bm){               // above diagonal: S never read there; seg = 0
    if (tid < 128) seg[((size_t)b*NSEG + bm)*SEQ + bn*128 + tid] = 0.f;
    return;
  }
  float* Sb = S0 + (size_t)b*SEQ*SEQ;
  __shared__ __align__(16) u16 As[128*32];
  __shared__ __align__(16) u16 Bs[128*32];
  __shared__ float cs[2][128];
  const int wv = tid>>6, ln = tid&63;
  const int lane15 = ln&15, quad = ln>>4;
  const int wm = wv&1, wn = wv>>1;
  f32x4 acc[4][4];
  f32x4 z = {0.f,0.f,0.f,0.f};
#pragma unroll
  for (int i=0;i<4;++i)
#pragma unroll
    for (int j=0;j<4;++j) acc[i][j] = z;
  const u16* Qb  = Qh  + (size_t)b*N_HEADS*SEQ*D_HEAD;   // head 0
  const u16* Kb  = Kh  + (size_t)b*N_HEADS*SEQ*D_HEAD;
  const u16* Qlb = Q0l + (size_t)b*SEQ*D_HEAD;
  const u16* Klb = K0l + (size_t)b*SEQ*D_HEAD;
  const u16* Aps[3] = {Qb, Qb, Qlb};
  const u16* Bps[3] = {Kb, Klb, Kb};
  const int sRow = ln>>2, sCol = (ln&3)*8;
  const size_t rowBase = (size_t)bm*128, colBase = (size_t)bn*128;
  for (int p = 0; p < 3; ++p) {
    const u16* Ap = Aps[p];
    const u16* Bp = Bps[p];
    for (int kt = 0; kt < 2; ++kt) {
      __syncthreads();
#pragma unroll
      for (int c = 0; c < 2; ++c) {
        int chunk = wv*2 + c;
        int r = chunk*16 + sRow;
        const u16* ga = Ap + (rowBase + r)*D_HEAD + kt*32 + sCol;
        const u16* gb = Bp + (colBase + r)*D_HEAD + kt*32 + sCol;
        __builtin_amdgcn_global_load_lds(
            (const __attribute__((address_space(1))) void*)ga,
            (__attribute__((address_space(3))) void*)(As + chunk*512), 16, 0, 0);
        __builtin_amdgcn_global_load_lds(
            (const __attribute__((address_space(1))) void*)gb,
            (__attribute__((address_space(3))) void*)(Bs + chunk*512), 16, 0, 0);
      }
      __syncthreads();
      bf16x8 af[4], bfb[4];
#pragma unroll
      for (int t=0;t<4;++t){
        af[t]  = *reinterpret_cast<const bf16x8*>(As + (wm*64 + t*16 + lane15)*32 + quad*8);
        bfb[t] = *reinterpret_cast<const bf16x8*>(Bs + (wn*64 + t*16 + lane15)*32 + quad*8);
      }
#pragma unroll
      for (int i=0;i<4;++i)
#pragma unroll
        for (int j=0;j<4;++j)
          acc[i][j] = __builtin_amdgcn_mfma_f32_16x16x32_bf16(af[i], bfb[j], acc[i][j], 0,0,0);
    }
  }
  float csum[4] = {0.f,0.f,0.f,0.f};
#pragma unroll
  for (int i=0;i<4;++i){
#pragma unroll
    for (int j=0;j<4;++j){
#pragma unroll
      for (int r=0;r<4;++r){
        int jg = (int)rowBase + wm*64 + i*16 + quad*4 + r;
        int mg = (int)colBase + wn*64 + j*16 + lane15;
        float l = acc[i][j][r]*0.125f;
        float s = (mg >= 1 && mg < jg) ? fmaxf(l, 0.f) : 0.f;
        Sb[(size_t)jg*SEQ + mg] = s;
        csum[j] += s;
      }
    }
  }
#pragma unroll
  for (int j=0;j<4;++j){
    float v = csum[j];
    v += __shfl_xor(v, 16);
    v += __shfl_xor(v, 32);
    if (ln < 16) cs[wm][wn*64 + j*16 + ln] = v;
  }
  __syncthreads();
  if (tid < 128)
    seg[((size_t)b*NSEG + bm)*SEQ + bn*128 + tid] = cs[0][tid] + cs[1][tid];
}

// -------------------- segmented exclusive cumsum over n --------------------
__global__ void k_seg_scan(float* __restrict__ seg){
  int m = blockIdx.x*256 + threadIdx.x;
  int b = blockIdx.y;
  float run = 0.f;
#pragma unroll
  for (int s=0;s<NSEG;++s){
    size_t idx = ((size_t)b*NSEG + s)*SEQ + m;
    float t = seg[idx]; seg[idx] = run; run += t;
  }
}
// in place: S -> -F*log2e (guard skips never-written above-diagonal cells)
__global__ void k_seg_apply(float* __restrict__ SF, const float* __restrict__ seg){
  int m = blockIdx.x*256 + threadIdx.x;
  int s = blockIdx.y, b = blockIdx.z;
  float run = seg[((size_t)b*NSEG + s)*SEQ + m];
  float* Sb = SF + (size_t)b*SEQ*SEQ;
  const int j0 = s*SEGLEN;
  for (int i=0;i<SEGLEN;++i){
    size_t idx = (size_t)(j0 + i)*SEQ + m;
    float t = Sb[idx];
    Sb[idx] = -run*LOG2E;
    run += (j0 + i > m) ? t : 0.f;
  }
}

// ------------- flash attention, fixed-max softmax, double-buffered ---------
__global__ __launch_bounds__(256, 4) void k_attn(
    const u16* __restrict__ Qh, const u16* __restrict__ Kh,
    const u16* __restrict__ Vt, const float* __restrict__ F,
    u16* __restrict__ Ob)
{
  __shared__ __align__(16) u16 Ks[2][64*64];
  __shared__ __align__(16) u16 Vs[2][64*64];
  const int h = blockIdx.x, b = blockIdx.z;
  const int nt = b ? (int)(gridDim.y - 1 - blockIdx.y) : (int)blockIdx.y;
  const int tid = threadIdx.x, wv = tid>>6, ln = tid&63;
  const int lane15 = ln&15, quad = ln>>4;
  const u16* Qbh = Qh + ((size_t)(b*N_HEADS + h))*SEQ*D_HEAD;
  const u16* Kbh = Kh + ((size_t)(b*N_HEADS + h))*SEQ*D_HEAD;
  const u16* Vbh = Vt + ((size_t)(b*N_HEADS + h))*D_HEAD*SEQ;
  const float* Fb = F + (size_t)b*SEQ*SEQ;
  const int n_loc = wv*16 + lane15;
  const int n_g = nt*64 + n_loc;
  const int swz = (ln&7) ^ ((ln>>3)&7);
  const int fswz = lane15 & 7;
  const int srow = ln>>3;

  bf16x8 qf[2];
#pragma unroll
  for (int kt=0; kt<2; ++kt)
    qf[kt] = *reinterpret_cast<const bf16x8*>(Qbh + (size_t)n_g*D_HEAD + kt*32 + quad*8);

  f32x4 z = {0.f,0.f,0.f,0.f};
  f32x4 psum = z;
  f32x4 acc_o[4];
#pragma unroll
  for (int no=0;no<4;++no) acc_o[no] = z;

  // stage K/V chunk mt into buffer buf
  auto stage = [&](int mt, int buf){
#pragma unroll
    for (int c=0;c<2;++c){
      int chunk = wv*2 + c;
      int r = chunk*8 + srow;
      const u16* gk = Kbh + (size_t)(mt*64 + r)*D_HEAD + swz*8;
      const u16* gv = Vbh + (size_t)r*SEQ + mt*64 + swz*8;
      __builtin_amdgcn_global_load_lds(
          (const __attribute__((address_space(1))) void*)gk,
          (__attribute__((address_space(3))) void*)(&Ks[buf][chunk*512]), 16, 0, 0);
      __builtin_amdgcn_global_load_lds(
          (const __attribute__((address_space(1))) void*)gv,
          (__attribute__((address_space(3))) void*)(&Vs[buf][chunk*512]), 16, 0, 0);
    }
  };
  stage(0, 0);
  const float c1 = 0.125f*LOG2E;

  for (int mt = 0; mt <= nt; ++mt) {
    const int cur = mt & 1;
    __syncthreads();                    // vmcnt(0) drain: buf[cur] ready
    if (mt < nt) stage(mt+1, 1-cur);    // prefetch next chunk (overlapped)
    // F prefetch for this chunk (already -F*log2e)
    const float* Fr = Fb + (size_t)n_g*SEQ + mt*64;
    f32x4 fv[4];
#pragma unroll
    for (int ms=0; ms<4; ++ms)
      fv[ms] = *reinterpret_cast<const f32x4*>(Fr + ms*16 + quad*4);
    // S^T chunk: rows m (4 x 16), col n = lane15
    f32x4 accs[4];
#pragma unroll
    for (int ms=0;ms<4;++ms) accs[ms] = z;
#pragma unroll
    for (int kt=0; kt<2; ++kt){
#pragma unroll
      for (int ms=0; ms<4; ++ms){
        bf16x8 a = *reinterpret_cast<const bf16x8*>(
            &Ks[cur][(ms*16 + lane15)*64 + (((kt*4 + quad) ^ fswz) * 8)]);
        accs[ms] = __builtin_amdgcn_mfma_f32_16x16x32_bf16(a, qf[kt], accs[ms], 0,0,0);
      }
    }
    // fixed-max softmax: p = exp2(score*log2e - F*log2e)
    const bool diag = (mt == nt);
    uint32_t pw[4][2];
#pragma unroll
    for (int ms=0; ms<4; ++ms){
      f32x4 t = accs[ms];
      float p[4];
#pragma unroll
      for (int r=0;r<4;++r){
        float l2 = fmaf(t[r], c1, fv[ms][r]);
        if (diag){
          int ml = ms*16 + quad*4 + r;
          l2 = (ml > n_loc) ? -1e30f : l2;
        }
        p[r] = __builtin_amdgcn_exp2f(l2);
      }
      psum[0]+=p[0]; psum[1]+=p[1]; psum[2]+=p[2]; psum[3]+=p[3];
      pw[ms][0] = pack2(p[0], p[1]);
      pw[ms][1] = pack2(p[2], p[3]);
    }
    // P relayout: C-layout (m=quad*4+r) -> A-fragment (k=quad*8+j) via shuffles
#pragma unroll
    for (int kt=0; kt<2; ++kt){
      union { uint32_t u[4]; bf16x8 v; } pa;
#pragma unroll
      for (int w=0; w<4; ++w){
        int sl = lane15 + 16*((quad&1)*2 + (w>>1));
        uint32_t t0 = (uint32_t)__shfl((int)pw[2*kt  ][w&1], sl);
        uint32_t t1 = (uint32_t)__shfl((int)pw[2*kt+1][w&1], sl);
        pa.u[w] = (quad < 2) ? t0 : t1;
      }
#pragma unroll
      for (int no=0; no<4; ++no){
        int d = no*16 + lane15;
        bf16x8 vb = *reinterpret_cast<const bf16x8*>(
            &Vs[cur][d*64 + (((kt*4 + quad) ^ (d&7)) * 8)]);
        acc_o[no] = __builtin_amdgcn_mfma_f32_16x16x32_bf16(pa.v, vb, acc_o[no], 0,0,0);
      }
    }
  }
  // deferred row-sum reduction; all lanes end with sum for row = lane15
  float s = (psum[0]+psum[1]) + (psum[2]+psum[3]);
  s += __shfl_xor(s, 16);
  s += __shfl_xor(s, 32);
  f32x4 inv;
#pragma unroll
  for (int r=0;r<4;++r)
    inv[r] = __builtin_amdgcn_rcpf(__shfl(s, quad*4 + r));
#pragma unroll
  for (int no=0; no<4; ++no){
#pragma unroll
    for (int r=0;r<4;++r){
      float o = acc_o[no][r] * inv[r];
      int row = nt*64 + wv*16 + quad*4 + r;
      Ob[((size_t)(b*SEQ + row))*D_MODEL + h*64 + no*16 + lane15] = f2bf(o);
    }
  }
}

// ------------------------ NT GEMM, 128x64 tile (O-proj) --------------------
__global__ __launch_bounds__(256) void k_gemm_nt64(
    const u16* __restrict__ A0, const u16* __restrict__ B0,
    float* __restrict__ C, int N, int K)
{
  __shared__ __align__(16) u16 As[128*32];
  __shared__ __align__(16) u16 Bs[64*32];
  const int tid = threadIdx.x, wv = tid>>6, ln = tid&63;
  const int lane15 = ln&15, quad = ln>>4;
  const int wm = wv&1, wn = wv>>1;
  const size_t rowBase = (size_t)blockIdx.y*128, colBase = (size_t)blockIdx.x*64;
  f32x4 acc[4][2];
  f32x4 z = {0.f,0.f,0.f,0.f};
#pragma unroll
  for (int i=0;i<4;++i){ acc[i][0] = z; acc[i][1] = z; }
  const int ktiles = K >> 5;
  const int sRow = ln>>2, sCol = (ln&3)*8;
  for (int kt = 0; kt < ktiles; ++kt) {
    __syncthreads();
#pragma unroll
    for (int c = 0; c < 2; ++c) {
      int chunk = wv*2 + c;
      int r = chunk*16 + sRow;
      const u16* ga = A0 + (rowBase + r)*K + kt*32 + sCol;
      __builtin_amdgcn_global_load_lds(
          (const __attribute__((address_space(1))) void*)ga,
          (__attribute__((address_space(3))) void*)(As + chunk*512), 16, 0, 0);
    }
    {
      int r = wv*16 + sRow;
      const u16* gb = B0 + (colBase + r)*K + kt*32 + sCol;
      __builtin_amdgcn_global_load_lds(
          (const __attribute__((address_space(1))) void*)gb,
          (__attribute__((address_space(3))) void*)(Bs + wv*512), 16, 0, 0);
    }
    __syncthreads();
    bf16x8 af[4], bfb[2];
#pragma unroll
    for (int t=0;t<4;++t)
      af[t]  = *reinterpret_cast<const bf16x8*>(As + (wm*64 + t*16 + lane15)*32 + quad*8);
#pragma unroll
    for (int t=0;t<2;++t)
      bfb[t] = *reinterpret_cast<const bf16x8*>(Bs + (wn*32 + t*16 + lane15)*32 + quad*8);
#pragma unroll
    for (int i=0;i<4;++i)
#pragma unroll
      for (int j=0;j<2;++j)
        acc[i][j] = __builtin_amdgcn_mfma_f32_16x16x32_bf16(af[i], bfb[j], acc[i][j], 0,0,0);
  }
#pragma unroll
  for (int i=0;i<4;++i){
    size_t row = rowBase + wm*64 + i*16 + quad*4;
#pragma unroll
    for (int j=0;j<2;++j){
      size_t col = colBase + wn*32 + j*16 + lane15;
#pragma unroll
      for (int r=0;r<4;++r)
        C[(row+r)*N + col] = acc[i][j][r];
    }
  }
}

// ------------------------------- launcher ----------------------------------
extern "C" void kernel_launch(void* const* d_in, const int* in_sizes, int n_in,
                              void* d_out, int out_size, void* d_ws, size_t ws_size,
                              hipStream_t stream)
{
  (void)in_sizes; (void)n_in; (void)out_size; (void)ws_size;
  const float* X  = (const float*)d_in[0];
  const float* Wq = (const float*)d_in[1];
  const float* Wk = (const float*)d_in[2];
  const float* Wv = (const float*)d_in[3];
  const float* Wo = (const float*)d_in[4];
  const float* gq = (const float*)d_in[5];
  const float* bq = (const float*)d_in[6];
  const float* gk = (const float*)d_in[7];
  const float* bk = (const float*)d_in[8];
  float* out = (float*)d_out;

  char* ws = (char*)d_ws;
  size_t off = 0;
  auto alloc = [&](size_t bytes)->char*{
    char* p = ws + off; off += (bytes + 255) & ~(size_t)255; return p;
  };
  u16* Xhi  = (u16*)alloc((size_t)ROWS*D_MODEL*2);
  u16* Xlo  = (u16*)alloc((size_t)ROWS*D_MODEL*2);
  u16* Wqkh = (u16*)alloc((size_t)2*D_MODEL*D_MODEL*2);  // [Wq;Wk] hi
  u16* Wqkl = (u16*)alloc((size_t)2*D_MODEL*D_MODEL*2);  // [Wq;Wk] lo
  u16* Wvb  = (u16*)alloc((size_t)D_MODEL*D_MODEL*2);
  u16* Wob  = (u16*)alloc((size_t)D_MODEL*D_MODEL*2);
  u16* Qhp  = (u16*)alloc((size_t)BATCH*N_HEADS*SEQ*D_HEAD*2);
  u16* Khp  = (u16*)alloc((size_t)BATCH*N_HEADS*SEQ*D_HEAD*2);
  u16* Q0l  = (u16*)alloc((size_t)BATCH*SEQ*D_HEAD*2);
  u16* K0l  = (u16*)alloc((size_t)BATCH*SEQ*D_HEAD*2);
  u16* Vtp  = (u16*)alloc((size_t)BATCH*N_HEADS*D_HEAD*SEQ*2);
  u16* Obf  = (u16*)alloc((size_t)ROWS*D_MODEL*2);
  float* Seg = (float*)alloc((size_t)BATCH*NSEG*SEQ*4);
  float* SF  = (float*)alloc((size_t)BATCH*SEQ*SEQ*4);   // 33.5 MB
  float* C32 = SF;    // QK-proj fp32 scratch aliases SF (consumed before s0)

  // casts (2 launches)
  k_cast_split_all<<<6144, 256, 0, stream>>>(
      X, Xhi, Xlo,
      Wq, Wqkh, Wqkl,
      Wk, Wqkh + (size_t)D_MODEL*D_MODEL, Wqkl + (size_t)D_MODEL*D_MODEL);
  k_cast2<<<2048, 256, 0, stream>>>(Wv, Wvb, Wo, Wob);

  // merged Q+K projection; head-0 col-tiles get 3-pass split precision
  k_gemm_qk<<<dim3(16, 32), 256, 0, stream>>>(Xhi, Xlo, Wqkh, Wqkl, C32);
  // both LNs + packs in one kernel
  k_ln_pack2<<<ROWS, 256, 0, stream>>>(C32, gq, bq, gk, bk, Qhp, Khp, Q0l, K0l);
  // V projection with fused V^T epilogue
  k_gemm_vt<<<dim3(16, 32), 256, 0, stream>>>(Xhi, Wvb, Vtp);
  // head-0 scores + fused segment sums; scan; apply (stores -F*log2e)
  k_s0<<<dim3(16, 16, BATCH), 256, 0, stream>>>(Qhp, Q0l, Khp, K0l, SF, Seg);
  k_seg_scan<<<dim3(8, BATCH), 256, 0, stream>>>(Seg);
  k_seg_apply<<<dim3(8, NSEG, BATCH), 256, 0, stream>>>(SF, Seg);
  // attention
  k_attn<<<dim3(N_HEADS, SEQ/64, BATCH), 256, 0, stream>>>(Qhp, Khp, Vtp, SF, Obf);
  // output projection
  k_gemm_nt64<<<dim3(16, 32), 256, 0, stream>>>(Obf, Wob, out, D_MODEL, D_MODEL);
}